// Round 12
// baseline (141.818 us; speedup 1.0000x reference)
//
#include <hip/hip_runtime.h>
#include <hip/hip_bf16.h>
#include <stdint.h>

typedef int v4i __attribute__((ext_vector_type(4)));

#define GPTR(p) ((const __attribute__((address_space(1))) void*)(p))
#define LPTR(p) ((__attribute__((address_space(3))) void*)(p))

__device__ __forceinline__ float wave_max(float m) {
#pragma unroll
  for (int off = 32; off > 0; off >>= 1)
    m = fmaxf(m, __shfl_xor(m, off, 64));
  return m;
}

// tanh-form GELU via sigmoid. |g - gelu_erf| <= ~3e-4. Validated r7.
__device__ __forceinline__ float gelu_tanh(float x) {
  const float x2 = x * x;
  const float u = x * fmaf(0.044715f, x2, 1.0f);
  const float e = exp2f(-2.3022082f * u);
  return x * __builtin_amdgcn_rcpf(1.0f + e);
}

// fused absmax of {x*smul, w1, w2} -> scal[0..2], one atomic per block
__global__ void absmax3_kernel(const float* __restrict__ x, int nx4,
                               const float* __restrict__ smul,
                               const float* __restrict__ w1, int nw14,
                               const float* __restrict__ w2, int nw24,
                               unsigned* __restrict__ scal) {
  __shared__ float red[4];
  const int bid = blockIdx.x;
  const float4* s4;
  int n4, b0, nb;
  float s = 1.0f;
  unsigned* dst;
  if (bid < 512)      { s4 = (const float4*)x;  n4 = nx4;  s = smul[0]; dst = scal;     b0 = bid;       nb = 512; }
  else if (bid < 640) { s4 = (const float4*)w1; n4 = nw14;              dst = scal + 1; b0 = bid - 512; nb = 128; }
  else                { s4 = (const float4*)w2; n4 = nw24;              dst = scal + 2; b0 = bid - 640; nb = 128; }
  float m = 0.0f;
  const int stride = nb * blockDim.x;
  for (int i = b0 * blockDim.x + threadIdx.x; i < n4; i += stride) {
    float4 v = s4[i];
    m = fmaxf(m, fabsf(v.x * s));
    m = fmaxf(m, fabsf(v.y * s));
    m = fmaxf(m, fabsf(v.z * s));
    m = fmaxf(m, fabsf(v.w * s));
  }
  m = wave_max(m);
  if ((threadIdx.x & 63) == 0) red[threadIdx.x >> 6] = m;
  __syncthreads();
  if (threadIdx.x == 0)
    atomicMax(dst, __float_as_uint(fmaxf(fmaxf(red[0], red[1]), fmaxf(red[2], red[3]))));
}

// fused quantize of {x*smul, w1, w2} -> qx, qw1, qw2
__global__ void quantize3_kernel(const float* __restrict__ x, int nx4,
                                 const float* __restrict__ smul,
                                 const float* __restrict__ w1, int nw14,
                                 const float* __restrict__ w2, int nw24,
                                 const unsigned* __restrict__ scal,
                                 int8_t* __restrict__ qx,
                                 int8_t* __restrict__ qw1,
                                 int8_t* __restrict__ qw2) {
  const int bid = blockIdx.x;
  const float4* s4;
  char4* d4;
  int n4, b0, nb;
  float s = 1.0f, mx;
  if (bid < 2048)      { s4 = (const float4*)x;  d4 = (char4*)qx;  n4 = nx4;  s = smul[0]; mx = __uint_as_float(scal[0]); b0 = bid;        nb = 2048; }
  else if (bid < 2176) { s4 = (const float4*)w1; d4 = (char4*)qw1; n4 = nw14;              mx = __uint_as_float(scal[1]); b0 = bid - 2048; nb = 128; }
  else                 { s4 = (const float4*)w2; d4 = (char4*)qw2; n4 = nw24;              mx = __uint_as_float(scal[2]); b0 = bid - 2176; nb = 128; }
  const float scale = mx / 127.0f;  // exact IEEE divide, matches reference
  const int stride = nb * blockDim.x;
  for (int i = b0 * blockDim.x + threadIdx.x; i < n4; i += stride) {
    float4 v = s4[i];
    char4 qq;
    qq.x = (signed char)(int)rintf(fminf(fmaxf((v.x * s) / scale, -128.0f), 127.0f));
    qq.y = (signed char)(int)rintf(fminf(fmaxf((v.y * s) / scale, -128.0f), 127.0f));
    qq.z = (signed char)(int)rintf(fminf(fmaxf((v.z * s) / scale, -128.0f), 127.0f));
    qq.w = (signed char)(int)rintf(fminf(fmaxf((v.w * s) / scale, -128.0f), 127.0f));
    d4[i] = qq;
  }
}

// reduce partial raw-f maxima -> s_h numerator = max|gelu| (r5-verified math)
__global__ void reduce_scale_kernel(const float* __restrict__ partial, int n,
                                    unsigned* __restrict__ scal) {
  __shared__ float red[4];
  float m = -3.4e38f;
  for (int i = threadIdx.x; i < n; i += blockDim.x) m = fmaxf(m, partial[i]);
  m = wave_max(m);
  if ((threadIdx.x & 63) == 0) red[threadIdx.x >> 6] = m;
  __syncthreads();
  if (threadIdx.x == 0) {
    m = fmaxf(fmaxf(red[0], red[1]), fmaxf(red[2], red[3]));
    const float sx = __uint_as_float(scal[0]) / 127.0f;
    const float sw = __uint_as_float(scal[1]) / 127.0f;
    const float max_f = m * (sw * sx);
    scal[3] = __float_as_uint(fmaxf(gelu_tanh(max_f), 0.1699702f));
  }
}

// ---------------------------------------------------------------------------
// fc1: C = qx[M,384] @ qw1[1536,384]^T, barrier-free wave-async K-loop.
// Block = 128(M) x 128(N); B panel resident in LDS (rows padded 384->400 B:
// bank-group = (r15+q4+c)&7 is perfectly uniform -> conflict-free b128 reads).
// Each wave owns a private 32-row A strip, double-buffered 2KB chunks via
// global_load_lds + per-wave counted vmcnt. NO barriers in the K-loop.
// EPI 0: per-block max of raw (int_max over m) + bias -> partial
// EPI 1: qh = rint(clip(gelu(f*s1)/s_h)) via wave-private swizzled repack
// ---------------------------------------------------------------------------
template <int EPI>
__global__ __launch_bounds__(256, 2)
void fc1_kernel(const int8_t* __restrict__ A, const int8_t* __restrict__ B,
                const float* __restrict__ bias, const unsigned* __restrict__ scal,
                float* __restrict__ partial, int8_t* __restrict__ qh,
                int N, int K, int GN) {
  __shared__ __align__(16) int8_t lB[128 * 400];   // 50 KB, padded rows
  __shared__ __align__(16) int8_t lAb[4 * 2 * 2048];  // per-wave dbuf (16 KB)
  __shared__ float red8[4];

  // bijective XCD swizzle (m204)
  const int nwg = gridDim.x;
  const int q = nwg >> 3, rr = nwg & 7;
  const int xcd = blockIdx.x & 7, sub = blockIdx.x >> 3;
  const int wg = (xcd < rr ? xcd * (q + 1) : rr * (q + 1) + (xcd - rr) * q) + sub;
  const int bx = wg % GN;   // n-tile fastest: shares A panel
  const int by = wg / GN;
  const int tid0 = by * GN + bx;

  const int t = threadIdx.x;
  const int lane = t & 63;
  const int wave = t >> 6;
  const int r15 = lane & 15;
  const int q4 = lane >> 4;
  const size_t m0 = (size_t)by * 128;
  const int n0 = bx * 128;
  const size_t ws0 = m0 + wave * 32;   // my wave's 32-row strip

  // ---- stage B panel once (reg-staged, padded rows) ----
  const int8_t* Bg = B + (size_t)n0 * K;
#pragma unroll
  for (int i = 0; i < 12; ++i) {
    const int chunk = i * 256 + t;        // 3072 chunks of 16 B
    const int row = chunk / 24;           // 24 x 16B per 384-B row
    const int col = chunk - row * 24;
    *(v4i*)(&lB[row * 400 + col * 16]) = *(const v4i*)(Bg + (size_t)chunk * 16);
  }

  // ---- per-lane A staging source offsets (r4-proven XOR slot swizzle) ----
  // load j: linear LDS byte o = j*1024 + lane*16; r = o>>6; ss = slot^((r>>1)&3)
  size_t srcA0, srcA1;
  {
    const int o0 = lane * 16;
    const int r0_ = o0 >> 6;
    const int ss0 = ((o0 >> 4) & 3) ^ ((r0_ >> 1) & 3);
    srcA0 = (ws0 + r0_) * (size_t)K + (size_t)(ss0 * 16);
    const int o1 = 1024 + lane * 16;
    const int r1_ = o1 >> 6;
    const int ss1 = ((o1 >> 4) & 3) ^ ((r1_ >> 1) & 3);
    srcA1 = (ws0 + r1_) * (size_t)K + (size_t)(ss1 * 16);
  }
  const int awbase = __builtin_amdgcn_readfirstlane(wave * 4096);

  auto stageA = [&](int buf, int kt) {
    const int8_t* g = A + kt * 64;
    __builtin_amdgcn_global_load_lds(GPTR(g + srcA0), LPTR(&lAb[awbase + buf * 2048]), 16, 0, 0);
    __builtin_amdgcn_global_load_lds(GPTR(g + srcA1), LPTR(&lAb[awbase + buf * 2048 + 1024]), 16, 0, 0);
  };

  // per-thread fragment read offsets
  int aoffc[2];
#pragma unroll
  for (int fr = 0; fr < 2; ++fr) {
    const int row = fr * 16 + r15;
    aoffc[fr] = row * 64 + ((q4 ^ ((row >> 1) & 3)) * 16);
  }
  const int bbase = r15 * 400 + q4 * 16;

  v4i acc[2][8] = {};
  const int KT = K >> 6;  // 6

  stageA(0, 0);
  __syncthreads();        // B panel ready (drains all staging)

  int cur = 0;
  for (int kt = 0; kt < KT; ++kt) {
    if (kt + 1 < KT) {
      stageA(cur ^ 1, kt + 1);
      asm volatile("s_waitcnt vmcnt(2)" ::: "memory");  // my chunk kt landed
    } else {
      asm volatile("s_waitcnt vmcnt(0)" ::: "memory");
    }
    v4i af[2], bf[8];
#pragma unroll
    for (int fr = 0; fr < 2; ++fr)
      af[fr] = *(const v4i*)(&lAb[awbase + cur * 2048 + aoffc[fr]]);
#pragma unroll
    for (int fc = 0; fc < 8; ++fc)
      bf[fc] = *(const v4i*)(&lB[bbase + fc * 6400 + kt * 64]);
#pragma unroll
    for (int fr = 0; fr < 2; ++fr)
#pragma unroll
      for (int fc = 0; fc < 8; ++fc)
        acc[fr][fc] = __builtin_amdgcn_mfma_i32_16x16x64_i8(af[fr], bf[fc], acc[fr][fc], 0, 0, 0);
    cur ^= 1;
  }

  // C frag layout (verified r1-r3): n = fc*16 + r15, m = fr*16 + q4*4 + reg
  if constexpr (EPI == 0) {
    float lm = -3.4e38f;
#pragma unroll
    for (int fc = 0; fc < 8; ++fc) {
      int im = acc[0][fc][0];
#pragma unroll
      for (int fr = 0; fr < 2; ++fr)
#pragma unroll
        for (int r = 0; r < 4; ++r) im = max(im, acc[fr][fc][r]);
      lm = fmaxf(lm, (float)im + bias[n0 + fc * 16 + r15]);
    }
    lm = wave_max(lm);
    if (lane == 0) red8[wave] = lm;
    __syncthreads();
    if (t == 0)
      partial[tid0] = fmaxf(fmaxf(red8[0], red8[1]), fmaxf(red8[2], red8[3]));
  } else {
    const float sx = __uint_as_float(scal[0]) / 127.0f;
    const float sw = __uint_as_float(scal[1]) / 127.0f;
    const float s1 = sw * sx;
    const float sh = __uint_as_float(scal[3]) / 127.0f;
    const float inv_sh = __builtin_amdgcn_rcpf(sh);
    // wave-private 32x128 repack tile in my A dbuf region (4 KB), swizzled
    int8_t* qt = &lAb[wave * 4096];
#pragma unroll
    for (int fc = 0; fc < 8; ++fc) {
      const int col = fc * 16 + r15;
      const float bvs = bias[n0 + col] * s1;
#pragma unroll
      for (int fr = 0; fr < 2; ++fr) {
        const int rowb = fr * 16 + q4 * 4;
#pragma unroll
        for (int r = 0; r < 4; ++r) {
          const float f = fmaf((float)acc[fr][fc][r], s1, bvs);
          const float g = gelu_tanh(f);
          const float qv = rintf(fminf(fmaxf(g * inv_sh, -128.0f), 127.0f));
          qt[(rowb + r) * 128 + (col ^ (q4 << 4))] = (int8_t)(int)qv;
        }
      }
    }
    // wave-private readout (no barrier): stored col' = col ^ (((row>>2)&3)<<4)
#pragma unroll
    for (int p = 0; p < 4; ++p) {
      const int row = p * 8 + (lane >> 3);
      const int colb = (lane & 7) * 16;
      const int swz = ((row >> 2) & 3) << 4;
      *(v4i*)(qh + (ws0 + row) * (size_t)N + n0 + colb) =
          *(const v4i*)(qt + row * 128 + (colb ^ swz));
    }
  }
}

#define CBAR()                          \
  do {                                  \
    __builtin_amdgcn_sched_barrier(0);  \
    __builtin_amdgcn_s_barrier();       \
    __builtin_amdgcn_sched_barrier(0);  \
  } while (0)

// gemm2 (fc2): r7-verified structure. BM=64, BN=128, BK=64, 2x2 waves,
// 2-buffer counted-vmcnt loop. out = (acc+b2)*s2 f32.
__global__ __launch_bounds__(256, 5)
void gemm2_out_kernel(const int8_t* __restrict__ A, const int8_t* __restrict__ B,
                      const float* __restrict__ bias, const unsigned* __restrict__ scal,
                      float* __restrict__ out_f32, int N, int K, int GN) {
  constexpr int BM = 64;
  constexpr int FR = 2;
  __shared__ __align__(16) int8_t lA[2][BM * 64];
  __shared__ __align__(16) int8_t lB[2][128 * 64];

  const int nwg = gridDim.x;
  const int q = nwg >> 3, rr = nwg & 7;
  const int xcd = blockIdx.x & 7, sub = blockIdx.x >> 3;
  const int wg = (xcd < rr ? xcd * (q + 1) : rr * (q + 1) + (xcd - rr) * q) + sub;
  const int bx = wg % GN;
  const int by = wg / GN;

  const int t = threadIdx.x;
  const int lane = t & 63;
  const int wave = t >> 6;
  const int wr = wave >> 1;
  const int wc = wave & 1;
  const size_t m0 = (size_t)by * BM;
  const int n0 = bx * 128;

  const int8_t* Ab = A + m0 * (size_t)K;
  const int8_t* Bb = B + (size_t)n0 * (size_t)K;

  v4i acc[FR][4] = {};
  const int KT = K >> 6;  // 24

  const int row0 = t >> 2;
  const int ss = (t & 3) ^ ((row0 >> 1) & 3);
  const int ubase = __builtin_amdgcn_readfirstlane((t & 192) * 16);
  const size_t srcA0 = (size_t)row0 * K + (size_t)(ss * 16);
  const size_t srcA1 = (size_t)(row0 + 64) * K + (size_t)(ss * 16);

  auto stage = [&](int buf, int kt) {
    const int8_t* ga = Ab + kt * 64;
    const int8_t* gb = Bb + kt * 64;
    __builtin_amdgcn_global_load_lds(GPTR(ga + srcA0), LPTR(&lA[buf][ubase]), 16, 0, 0);
    __builtin_amdgcn_global_load_lds(GPTR(gb + srcA0), LPTR(&lB[buf][ubase]), 16, 0, 0);
    __builtin_amdgcn_global_load_lds(GPTR(gb + srcA1), LPTR(&lB[buf][4096 + ubase]), 16, 0, 0);
  };

  const int r15 = lane & 15;
  const int q4 = lane >> 4;

  auto compute = [&](int buf) {
    v4i af[FR], bf[4];
#pragma unroll
    for (int fr = 0; fr < FR; ++fr) {
      const int row = wr * (BM / 2) + fr * 16 + r15;
      const int slot = q4 ^ ((row >> 1) & 3);
      af[fr] = *(const v4i*)(&lA[buf][row * 64 + slot * 16]);
    }
#pragma unroll
    for (int fc = 0; fc < 4; ++fc) {
      const int row = wc * 64 + fc * 16 + r15;
      const int slot = q4 ^ ((row >> 1) & 3);
      bf[fc] = *(const v4i*)(&lB[buf][row * 64 + slot * 16]);
    }
#pragma unroll
    for (int fr = 0; fr < FR; ++fr)
#pragma unroll
      for (int fc = 0; fc < 4; ++fc)
        acc[fr][fc] = __builtin_amdgcn_mfma_i32_16x16x64_i8(af[fr], bf[fc], acc[fr][fc], 0, 0, 0);
  };

  stage(0, 0);
  int cur = 0;
  for (int kt = 0; kt < KT; ++kt) {
    if (kt + 1 < KT) {
      stage(cur ^ 1, kt + 1);
      asm volatile("s_waitcnt vmcnt(3)" ::: "memory");
    } else {
      asm volatile("s_waitcnt vmcnt(0)" ::: "memory");
    }
    CBAR();
    compute(cur);
    if (kt + 1 < KT) {
      asm volatile("s_waitcnt lgkmcnt(0)" ::: "memory");
      CBAR();
    }
    cur ^= 1;
  }

  const int rb = q4 * 4;
  const float sw2 = __uint_as_float(scal[2]) / 127.0f;
  const float sh = __uint_as_float(scal[3]) / 127.0f;
  const float s2 = sw2 * ((127.0f * sh) / 127.0f);
#pragma unroll
  for (int fc = 0; fc < 4; ++fc) {
    const int n = n0 + wc * 64 + fc * 16 + r15;
    const float bvs = bias[n] * s2;
#pragma unroll
    for (int fr = 0; fr < FR; ++fr)
#pragma unroll
      for (int r = 0; r < 4; ++r) {
        const size_t m = m0 + (size_t)(wr * (BM / 2) + fr * 16 + rb + r);
        out_f32[m * (size_t)N + n] = fmaf((float)acc[fr][fc][r], s2, bvs);
      }
  }
}

extern "C" void kernel_launch(void* const* d_in, const int* in_sizes, int n_in,
                              void* d_out, int out_size, void* d_ws, size_t ws_size,
                              hipStream_t stream) {
  const float* x   = (const float*)d_in[0];
  const float* sxp = (const float*)d_in[1];
  const float* w1  = (const float*)d_in[2];
  const float* b1  = (const float*)d_in[3];
  const float* w2  = (const float*)d_in[4];
  const float* b2  = (const float*)d_in[5];

  const int H = in_sizes[3];      // 1536
  const int D = in_sizes[5];      // 384
  const int M = in_sizes[0] / D;  // 25216 = 197*128
  const int GM1 = M / 128;        // 197
  const int GM2 = M / 64;         // 394
  const int GN1 = H / 128;        // 12
  const int GN2 = D / 128;        // 3

  uint8_t* ws = (uint8_t*)d_ws;
  unsigned* scal = (unsigned*)ws;  // [0]=max|x2| [1]=max|w1| [2]=max|w2| [3]=max|g|
  size_t off = 256;
  float* partial = (float*)(ws + off); off += 16384;
  int8_t* qx  = (int8_t*)(ws + off); off += (size_t)M * D;
  int8_t* qw1 = (int8_t*)(ws + off); off += (size_t)H * D;
  int8_t* qw2 = (int8_t*)(ws + off); off += (size_t)D * H;
  int8_t* qh  = (int8_t*)(ws + off); off += (size_t)M * H;
  (void)ws_size; (void)n_in; (void)out_size;

  hipMemsetAsync(scal, 0, 16, stream);

  absmax3_kernel<<<dim3(768), dim3(256), 0, stream>>>(
      x, M * D / 4, sxp, w1, H * D / 4, w2, D * H / 4, scal);

  quantize3_kernel<<<dim3(2304), dim3(256), 0, stream>>>(
      x, M * D / 4, sxp, w1, H * D / 4, w2, D * H / 4, scal, qx, qw1, qw2);

  dim3 blk(256);
  dim3 g1(GN1 * GM1);  // 2364
  fc1_kernel<0><<<g1, blk, 0, stream>>>(qx, qw1, b1, scal, partial, nullptr, H, D, GN1);
  reduce_scale_kernel<<<1, 256, 0, stream>>>(partial, GM1 * GN1, scal);
  fc1_kernel<1><<<g1, blk, 0, stream>>>(qx, qw1, b1, scal, nullptr, qh, H, D, GN1);

  dim3 g2(GN2 * GM2);  // 1182
  gemm2_out_kernel<<<g2, blk, 0, stream>>>(qh, qw2, b2, scal, (float*)d_out, D, H, GN2);
}

// Round 13
// 131.964 us; speedup vs baseline: 1.0747x; 1.0747x over previous
//
#include <hip/hip_runtime.h>
#include <hip/hip_bf16.h>
#include <stdint.h>

typedef int v4i __attribute__((ext_vector_type(4)));

#define GPTR(p) ((const __attribute__((address_space(1))) void*)(p))
#define LPTR(p) ((__attribute__((address_space(3))) void*)(p))

__device__ __forceinline__ float wave_max(float m) {
#pragma unroll
  for (int off = 32; off > 0; off >>= 1)
    m = fmaxf(m, __shfl_xor(m, off, 64));
  return m;
}

// tanh-form GELU via sigmoid. |g - gelu_erf| <= ~3e-4. Validated r7.
__device__ __forceinline__ float gelu_tanh(float x) {
  const float x2 = x * x;
  const float u = x * fmaf(0.044715f, x2, 1.0f);
  const float e = exp2f(-2.3022082f * u);
  return x * __builtin_amdgcn_rcpf(1.0f + e);
}

// fused absmax of {x*smul, w1, w2} -> scal[0..2], one atomic per block
__global__ void absmax3_kernel(const float* __restrict__ x, int nx4,
                               const float* __restrict__ smul,
                               const float* __restrict__ w1, int nw14,
                               const float* __restrict__ w2, int nw24,
                               unsigned* __restrict__ scal) {
  __shared__ float red[4];
  const int bid = blockIdx.x;
  const float4* s4;
  int n4, b0, nb;
  float s = 1.0f;
  unsigned* dst;
  if (bid < 512)      { s4 = (const float4*)x;  n4 = nx4;  s = smul[0]; dst = scal;     b0 = bid;       nb = 512; }
  else if (bid < 640) { s4 = (const float4*)w1; n4 = nw14;              dst = scal + 1; b0 = bid - 512; nb = 128; }
  else                { s4 = (const float4*)w2; n4 = nw24;              dst = scal + 2; b0 = bid - 640; nb = 128; }
  float m = 0.0f;
  const int stride = nb * blockDim.x;
  for (int i = b0 * blockDim.x + threadIdx.x; i < n4; i += stride) {
    float4 v = s4[i];
    m = fmaxf(m, fabsf(v.x * s));
    m = fmaxf(m, fabsf(v.y * s));
    m = fmaxf(m, fabsf(v.z * s));
    m = fmaxf(m, fabsf(v.w * s));
  }
  m = wave_max(m);
  if ((threadIdx.x & 63) == 0) red[threadIdx.x >> 6] = m;
  __syncthreads();
  if (threadIdx.x == 0)
    atomicMax(dst, __float_as_uint(fmaxf(fmaxf(red[0], red[1]), fmaxf(red[2], red[3]))));
}

// fused quantize of {x*smul, w1, w2} -> qx, qw1, qw2
__global__ void quantize3_kernel(const float* __restrict__ x, int nx4,
                                 const float* __restrict__ smul,
                                 const float* __restrict__ w1, int nw14,
                                 const float* __restrict__ w2, int nw24,
                                 const unsigned* __restrict__ scal,
                                 int8_t* __restrict__ qx,
                                 int8_t* __restrict__ qw1,
                                 int8_t* __restrict__ qw2) {
  const int bid = blockIdx.x;
  const float4* s4;
  char4* d4;
  int n4, b0, nb;
  float s = 1.0f, mx;
  if (bid < 2048)      { s4 = (const float4*)x;  d4 = (char4*)qx;  n4 = nx4;  s = smul[0]; mx = __uint_as_float(scal[0]); b0 = bid;        nb = 2048; }
  else if (bid < 2176) { s4 = (const float4*)w1; d4 = (char4*)qw1; n4 = nw14;              mx = __uint_as_float(scal[1]); b0 = bid - 2048; nb = 128; }
  else                 { s4 = (const float4*)w2; d4 = (char4*)qw2; n4 = nw24;              mx = __uint_as_float(scal[2]); b0 = bid - 2176; nb = 128; }
  const float scale = mx / 127.0f;  // exact IEEE divide, matches reference
  const int stride = nb * blockDim.x;
  for (int i = b0 * blockDim.x + threadIdx.x; i < n4; i += stride) {
    float4 v = s4[i];
    char4 qq;
    qq.x = (signed char)(int)rintf(fminf(fmaxf((v.x * s) / scale, -128.0f), 127.0f));
    qq.y = (signed char)(int)rintf(fminf(fmaxf((v.y * s) / scale, -128.0f), 127.0f));
    qq.z = (signed char)(int)rintf(fminf(fmaxf((v.z * s) / scale, -128.0f), 127.0f));
    qq.w = (signed char)(int)rintf(fminf(fmaxf((v.w * s) / scale, -128.0f), 127.0f));
    d4[i] = qq;
  }
}

// reduce partial raw-f maxima -> s_h numerator = max|gelu| (r5-verified math)
__global__ void reduce_scale_kernel(const float* __restrict__ partial, int n,
                                    unsigned* __restrict__ scal) {
  __shared__ float red[4];
  float m = -3.4e38f;
  for (int i = threadIdx.x; i < n; i += blockDim.x) m = fmaxf(m, partial[i]);
  m = wave_max(m);
  if ((threadIdx.x & 63) == 0) red[threadIdx.x >> 6] = m;
  __syncthreads();
  if (threadIdx.x == 0) {
    m = fmaxf(fmaxf(red[0], red[1]), fmaxf(red[2], red[3]));
    const float sx = __uint_as_float(scal[0]) / 127.0f;
    const float sw = __uint_as_float(scal[1]) / 127.0f;
    const float max_f = m * (sw * sx);
    scal[3] = __float_as_uint(fmaxf(gelu_tanh(max_f), 0.1699702f));
  }
}

// ---------------------------------------------------------------------------
// GEMM: C = A[M,K] @ B[N,K]^T, int8 -> int32 MFMA.
// 512 threads = 8 waves (4M x 2N), tile 128x128, BK=64, 2-buffer 1-barrier
// loop (r2-verified). Each wave owns a 32x64 output subtile (2x4 frags,
// 8 MFMA/kt). Staging = exactly 1 global_load_lds per thread per array.
// C frag layout (verified r1-r3): n = fc*16 + (lane&15),
//                                 m = wr*32 + fr*16 + (lane>>4)*4 + reg.
// EPI 0: per-block max of raw int-max(acc)+bias -> partial
// EPI 1: qh = rint(clip(gelu(f*s1)/s_h)) int8 via swizzled LDS repack
// EPI 2: out = (acc+b2)*s2 f32 direct stores
// ---------------------------------------------------------------------------
template <int EPI>
__device__ __forceinline__
void gemm_body(const int8_t* __restrict__ A, const int8_t* __restrict__ B,
               const float* __restrict__ bias, const unsigned* __restrict__ scal,
               float* __restrict__ partial, int8_t* __restrict__ out_i8,
               float* __restrict__ out_f32, int N, int K, int GN) {
  __shared__ __align__(16) int8_t lA[2][128 * 64];
  __shared__ __align__(16) int8_t lB[2][128 * 64];
  __shared__ float red8[8];

  // bijective XCD swizzle (m204)
  const int nwg = gridDim.x;
  const int q = nwg >> 3, rr = nwg & 7;
  const int xcd = blockIdx.x & 7, sub = blockIdx.x >> 3;
  const int wg = (xcd < rr ? xcd * (q + 1) : rr * (q + 1) + (xcd - rr) * q) + sub;
  const int bx = wg % GN;   // n-tile fastest: shares A panel
  const int by = wg / GN;
  const int tid0 = by * GN + bx;

  const int t = threadIdx.x;
  const int lane = t & 63;
  const int wave = t >> 6;      // 0..7
  const int wr = wave >> 1;     // 0..3 (M)
  const int wc = wave & 1;      // 0..1 (N)
  const size_t m0 = (size_t)by * 128;
  const int n0 = bx * 128;

  const int8_t* Ab = A + m0 * (size_t)K;
  const int8_t* Bb = B + (size_t)n0 * (size_t)K;

  v4i acc[2][4] = {};
  const int KT = K >> 6;  // 6 (fc1) or 24 (fc2)

  // Staging: linear LDS fill (1 load/thread/array); XOR slot-swizzle
  // f(row)=(row>>1)&3 pre-applied on the GLOBAL source (both-sides rule,
  // 0 conflicts measured r4-r7). 64B rows = 4 x 16B slots; 512 threads
  // cover all 128 rows.
  const int row0 = t >> 2;                      // 0..127
  const int ss = (t & 3) ^ ((row0 >> 1) & 3);
  const int ubase = __builtin_amdgcn_readfirstlane(wave * 1024);  // wave base
  const size_t srcA0 = (size_t)row0 * K + (size_t)(ss * 16);

  auto stage = [&](int buf, int kt) {
    const int8_t* ga = Ab + kt * 64;
    const int8_t* gb = Bb + kt * 64;
    __builtin_amdgcn_global_load_lds(GPTR(ga + srcA0), LPTR(&lA[buf][ubase]), 16, 0, 0);
    __builtin_amdgcn_global_load_lds(GPTR(gb + srcA0), LPTR(&lB[buf][ubase]), 16, 0, 0);
  };

  const int r15 = lane & 15;
  const int q4 = lane >> 4;

  auto compute = [&](int buf) {
    v4i af[2], bf[4];
#pragma unroll
    for (int fr = 0; fr < 2; ++fr) {
      const int row = wr * 32 + fr * 16 + r15;
      const int slot = q4 ^ ((row >> 1) & 3);
      af[fr] = *(const v4i*)(&lA[buf][row * 64 + slot * 16]);
    }
#pragma unroll
    for (int fc = 0; fc < 4; ++fc) {
      const int row = wc * 64 + fc * 16 + r15;
      const int slot = q4 ^ ((row >> 1) & 3);
      bf[fc] = *(const v4i*)(&lB[buf][row * 64 + slot * 16]);
    }
#pragma unroll
    for (int fr = 0; fr < 2; ++fr)
#pragma unroll
      for (int fc = 0; fc < 4; ++fc)
        acc[fr][fc] = __builtin_amdgcn_mfma_i32_16x16x64_i8(af[fr], bf[fc], acc[fr][fc], 0, 0, 0);
  };

  // r2-verified simple loop: 1 barrier per kt (implicit full drain).
  stage(0, 0);
  __syncthreads();
  int cur = 0;
  for (int kt = 1; kt < KT; ++kt) {
    stage(cur ^ 1, kt);   // issue next-tile loads BEFORE compute
    compute(cur);
    __syncthreads();      // drains vmcnt+lgkmcnt: next tile ready
    cur ^= 1;
  }
  compute(cur);

  const int rb = q4 * 4;

  if constexpr (EPI == 0) {
    // max over m of (acc+bias) = int-max over m, then one add per column.
    float lm = -3.4e38f;
#pragma unroll
    for (int fc = 0; fc < 4; ++fc) {
      int im = acc[0][fc][0];
#pragma unroll
      for (int fr = 0; fr < 2; ++fr)
#pragma unroll
        for (int r = 0; r < 4; ++r) im = max(im, acc[fr][fc][r]);
      lm = fmaxf(lm, (float)im + bias[n0 + wc * 64 + fc * 16 + r15]);
    }
    lm = wave_max(lm);
    if (lane == 0) red8[wave] = lm;
    __syncthreads();
    if (t == 0) {
      float bm = red8[0];
#pragma unroll
      for (int w = 1; w < 8; ++w) bm = fmaxf(bm, red8[w]);
      partial[tid0] = bm;
    }
  } else if constexpr (EPI == 1) {
    const float sx = __uint_as_float(scal[0]) / 127.0f;
    const float sw = __uint_as_float(scal[1]) / 127.0f;
    const float s1 = sw * sx;
    const float sh = __uint_as_float(scal[3]) / 127.0f;
    const float inv_sh = __builtin_amdgcn_rcpf(sh);
    __syncthreads();                 // all compute() LDS reads complete
    int8_t* qt = (int8_t*)lA;        // 16 KiB repack tile, swizzled (r6: 0 conf)
#pragma unroll
    for (int fc = 0; fc < 4; ++fc) {
      const int col = wc * 64 + fc * 16 + r15;
      const float bvs = bias[n0 + col] * s1;
#pragma unroll
      for (int fr = 0; fr < 2; ++fr) {
        const int rowb = wr * 32 + fr * 16 + rb;
#pragma unroll
        for (int r = 0; r < 4; ++r) {
          const float f = fmaf((float)acc[fr][fc][r], s1, bvs);
          const float g = gelu_tanh(f);
          const float qv = rintf(fminf(fmaxf(g * inv_sh, -128.0f), 127.0f));
          qt[(rowb + r) * 128 + (col ^ (q4 << 4))] = (int8_t)(int)qv;
        }
      }
    }
    __syncthreads();
#pragma unroll
    for (int v = 0; v < 2; ++v) {
      const int idx = v * 512 + t;
      const int row = idx >> 3;
      const int colb = (idx & 7) * 16;
      const int swz = ((row >> 2) & 3) << 4;
      *(v4i*)(out_i8 + (m0 + row) * (size_t)N + n0 + colb) =
          *(const v4i*)(qt + row * 128 + (colb ^ swz));
    }
  } else {
    const float sw2 = __uint_as_float(scal[2]) / 127.0f;
    const float sh = __uint_as_float(scal[3]) / 127.0f;
    const float s2 = sw2 * ((127.0f * sh) / 127.0f);
#pragma unroll
    for (int fc = 0; fc < 4; ++fc) {
      const int n = n0 + wc * 64 + fc * 16 + r15;
      const float bvs = bias[n] * s2;
#pragma unroll
      for (int fr = 0; fr < 2; ++fr)
#pragma unroll
        for (int r = 0; r < 4; ++r) {
          const size_t m = m0 + (size_t)(wr * 32 + fr * 16 + rb + r);
          out_f32[m * (size_t)N + n] = fmaf((float)acc[fr][fc][r], s2, bvs);
        }
    }
  }
}

__global__ __launch_bounds__(512, 4)
void gemm1_absmax_kernel(const int8_t* A, const int8_t* B, const float* bias,
                         const unsigned* scal, float* partial, int N, int K, int GN) {
  gemm_body<0>(A, B, bias, scal, partial, nullptr, nullptr, N, K, GN);
}

__global__ __launch_bounds__(512, 4)
void gemm1_quant_kernel(const int8_t* A, const int8_t* B, const float* bias,
                        const unsigned* scal, int8_t* out_i8, int N, int K, int GN) {
  gemm_body<1>(A, B, bias, scal, nullptr, out_i8, nullptr, N, K, GN);
}

__global__ __launch_bounds__(512, 4)
void gemm2_out_kernel(const int8_t* A, const int8_t* B, const float* bias,
                      const unsigned* scal, float* out_f32, int N, int K, int GN) {
  gemm_body<2>(A, B, bias, scal, nullptr, nullptr, out_f32, N, K, GN);
}

extern "C" void kernel_launch(void* const* d_in, const int* in_sizes, int n_in,
                              void* d_out, int out_size, void* d_ws, size_t ws_size,
                              hipStream_t stream) {
  const float* x   = (const float*)d_in[0];
  const float* sxp = (const float*)d_in[1];
  const float* w1  = (const float*)d_in[2];
  const float* b1  = (const float*)d_in[3];
  const float* w2  = (const float*)d_in[4];
  const float* b2  = (const float*)d_in[5];

  const int H = in_sizes[3];      // 1536
  const int D = in_sizes[5];      // 384
  const int M = in_sizes[0] / D;  // 25216 = 197*128
  const int GM = M / 128;         // 197
  const int GN1 = H / 128;        // 12
  const int GN2 = D / 128;        // 3

  uint8_t* ws = (uint8_t*)d_ws;
  unsigned* scal = (unsigned*)ws;  // [0]=max|x2| [1]=max|w1| [2]=max|w2| [3]=max|g|
  size_t off = 256;
  float* partial = (float*)(ws + off); off += 16384;
  int8_t* qx  = (int8_t*)(ws + off); off += (size_t)M * D;
  int8_t* qw1 = (int8_t*)(ws + off); off += (size_t)H * D;
  int8_t* qw2 = (int8_t*)(ws + off); off += (size_t)D * H;
  int8_t* qh  = (int8_t*)(ws + off); off += (size_t)M * H;
  (void)ws_size; (void)n_in; (void)out_size;

  hipMemsetAsync(scal, 0, 16, stream);

  absmax3_kernel<<<dim3(768), dim3(256), 0, stream>>>(
      x, M * D / 4, sxp, w1, H * D / 4, w2, D * H / 4, scal);

  quantize3_kernel<<<dim3(2304), dim3(256), 0, stream>>>(
      x, M * D / 4, sxp, w1, H * D / 4, w2, D * H / 4, scal, qx, qw1, qw2);

  dim3 blk(512);
  dim3 g1(GN1 * GM);  // 2364
  gemm1_absmax_kernel<<<g1, blk, 0, stream>>>(qx, qw1, b1, scal, partial, H, D, GN1);
  reduce_scale_kernel<<<1, 256, 0, stream>>>(partial, GM * GN1, scal);
  gemm1_quant_kernel<<<g1, blk, 0, stream>>>(qx, qw1, b1, scal, qh, H, D, GN1);

  dim3 g2(GN2 * GM);  // 591
  gemm2_out_kernel<<<g2, blk, 0, stream>>>(qh, qw2, b2, scal, (float*)d_out, D, H, GN2);
}